// Round 12
// baseline (151.490 us; speedup 1.0000x reference)
//
#include <hip/hip_runtime.h>

#define NSEQ 4096
#define EDIM 1024

// Cross-dispatch intermediates in __device__ globals (round 10: harness
// re-poisons d_ws unconditionally; globals are clean and cost nothing).
// Every element is fully rewritten each iteration before any read.
__device__ float  g_pbx[4 * 64 * NSEQ];   // partial Bx [4 q][64 chain][4096 t]
__device__ float2 g_hp [64 * NSEQ];       // {h_loc, P_inc} [64 chain][4096 t]
__device__ float2 g_sum[64 * 16];         // {h_last, P_prod} [64 chain][16 chunk]

__device__ __forceinline__ void fma4(float4& a, float xv, const float4& b) {
    a.x = fmaf(xv, b.x, a.x);
    a.y = fmaf(xv, b.y, a.y);
    a.z = fmaf(xv, b.z, a.z);
    a.w = fmaf(xv, b.w, a.w);
}

// ---------------------------------------------------------------------------
// k1: partial Bx = x @ B_in over one e-quarter. 1024 blocks x 256 threads,
// 4 blocks/CU. CHANGE (single-variable vs round 10): x is no longer loaded
// lane=row SCATTERED (64 x 16B requests to 4KB-spaced lines per instruction
// = 16384 L1/TA requests per CU ~= the whole 30 us k1 duration); instead each
// WAVE stages its own 64-row x 16-e slice through a PRIVATE double-buffered
// LDS tile: global loads become 16x64B segments per instruction (~8-16x
// fewer TA requests), ds_reads are conflict-free (pitch 17: (17*lane)%32
// covers 2 lanes/bank = free). NO __syncthreads in the main loop — the
// pipeline (issue loads c+1 -> compute c -> ds_write c+1) is ordered purely
// by this wave's own vmcnt/lgkmcnt, so waves never lockstep (the round-2
// staged variant died on barrier+vmcnt(0) lockstep).
// B stays on the scalar path (R9/R11: B-path is perf-neutral both ways).
// LDS 34.8 KB: [4 waves][2 bufs][64 rows][17]; reduction aliases each
// wave's own buf0 (dead after chunk 2). One barrier total.
// ---------------------------------------------------------------------------
__global__ __launch_bounds__(256, 4) void k1_bx(const float* __restrict__ x,
                                                const float* __restrict__ Bin) {
    __shared__ __align__(16) float smem[4 * 2 * 64 * 17];   // 34816 B
    const int tid  = threadIdx.x;
    const int lane = tid & 63;                                  // row
    const int wu   = __builtin_amdgcn_readfirstlane(tid) >> 6;  // wave id
    const int q    = blockIdx.x & 3;                            // e-quarter
    const int r0   = (blockIdx.x >> 2) * 64;                    // row base
    const int b    = r0 >> 12;
    const int n0   = r0 & 4095;
    const int eq   = q * 256;

    const float4* xf4 = (const float4*)x;
    const float4* Bf4 = (const float4*)Bin;

    const int wbase = wu * 2176;        // this wave's private dbuf region
    const int srow  = lane >> 2;        // staging rows: srow + 16k
    const int sc4   = lane & 3;         // staging float4-within-16e

    float4 pf[4];
    // prologue: stage chunk 0 (coalesced: lanes 0..3 = 64B of one row)
#pragma unroll
    for (int k = 0; k < 4; k++)
        pf[k] = xf4[(size_t)(r0 + srow + 16 * k) * 256 + q * 64 + wu * 4 + sc4];
#pragma unroll
    for (int k = 0; k < 4; k++)
        *(float4*)&smem[wbase + (srow + 16 * k) * 17 + sc4 * 4] = pf[k];

    float acc[16];
#pragma unroll
    for (int s = 0; s < 16; s++) acc[s] = 0.f;

    for (int c = 0; c < 4; ++c) {
        if (c < 3) {   // issue chunk c+1 loads (no dependency on compute)
#pragma unroll
            for (int k = 0; k < 4; k++)
                pf[k] = xf4[(size_t)(r0 + srow + 16 * k) * 256 + q * 64 +
                            (c + 1) * 16 + wu * 4 + sc4];
        }
        __builtin_amdgcn_sched_barrier(0);   // loads issued before compute

        const float* buf = &smem[wbase + (c & 1) * 1088];
#pragma unroll
        for (int el = 0; el < 16; ++el) {
            const float xv = buf[lane * 17 + el];          // conflict-free b32
            const int e = eq + c * 64 + wu * 16 + el;      // wave-uniform
            const float4 b0 = Bf4[e * 4 + 0];
            const float4 b1 = Bf4[e * 4 + 1];
            const float4 b2 = Bf4[e * 4 + 2];
            const float4 b3 = Bf4[e * 4 + 3];
            acc[0]  = fmaf(xv, b0.x, acc[0]);  acc[1]  = fmaf(xv, b0.y, acc[1]);
            acc[2]  = fmaf(xv, b0.z, acc[2]);  acc[3]  = fmaf(xv, b0.w, acc[3]);
            acc[4]  = fmaf(xv, b1.x, acc[4]);  acc[5]  = fmaf(xv, b1.y, acc[5]);
            acc[6]  = fmaf(xv, b1.z, acc[6]);  acc[7]  = fmaf(xv, b1.w, acc[7]);
            acc[8]  = fmaf(xv, b2.x, acc[8]);  acc[9]  = fmaf(xv, b2.y, acc[9]);
            acc[10] = fmaf(xv, b2.z, acc[10]); acc[11] = fmaf(xv, b2.w, acc[11]);
            acc[12] = fmaf(xv, b3.x, acc[12]); acc[13] = fmaf(xv, b3.y, acc[13]);
            acc[14] = fmaf(xv, b3.z, acc[14]); acc[15] = fmaf(xv, b3.w, acc[15]);
        }

        __builtin_amdgcn_sched_barrier(0);   // keep ds_write AFTER compute
        if (c < 3) {   // write chunk c+1 into the other private buffer
            float* dst = &smem[wbase + ((c + 1) & 1) * 1088];
#pragma unroll
            for (int k = 0; k < 4; k++)
                *(float4*)&dst[(srow + 16 * k) * 17 + sc4 * 4] = pf[k];
        }
    }

    // wave writes its acc into its OWN buf0 (free after chunk 2's compute;
    // chunk 3 read buf1) -> no cross-wave hazard before the single barrier.
    {
        const int rb = wbase + lane * 17;
#pragma unroll
        for (int s = 0; s < 16; s++) smem[rb + s] = acc[s];
    }
    __syncthreads();

#pragma unroll
    for (int p = 0; p < 4; p++) {
        const int o   = tid + 256 * p;
        const int s   = o >> 6;      // wave-uniform
        const int row = o & 63;
        const float v = smem[0 * 2176 + row * 17 + s] + smem[1 * 2176 + row * 17 + s] +
                        smem[2 * 2176 + row * 17 + s] + smem[3 * 2176 + row * 17 + s];
        g_pbx[(size_t)q * 262144u + (size_t)(b * 16 + s) * NSEQ + n0 + row] = v;
    }
}

// ---------------------------------------------------------------------------
// k2: sum 4 partial-Bx quarters, softplus -> decay, 256-wide chunk-local
// scan. 1024 blocks x 256 threads. (unchanged from round 10)
// ---------------------------------------------------------------------------
__global__ __launch_bounds__(256) void k2_scan(const float* __restrict__ A) {
    __shared__ float sP[4], sH[4];
    const int tid   = threadIdx.x;
    const int lane  = tid & 63;
    const int w     = tid >> 6;
    const int chain = blockIdx.x >> 4;
    const int chunk = blockIdx.x & 15;
    const int ss    = chain & 15;
    const int t     = chunk * 256 + tid;

    float bxv = 0.f;
#pragma unroll
    for (int q = 0; q < 4; q++)
        bxv += g_pbx[(size_t)q * 262144u + (size_t)chain * NSEQ + t];

    const float Ae = expf(A[ss]);
    const float sp = fmaxf(bxv, 0.f) + log1pf(expf(-fabsf(bxv)));
    const float de = expf(-Ae * sp);

    float Pi = de, hi = bxv;
#pragma unroll
    for (int off = 1; off < 64; off <<= 1) {
        float Pp = __shfl_up(Pi, off, 64);
        float hp = __shfl_up(hi, off, 64);
        if (lane >= off) { hi = fmaf(hp, Pi, hi); Pi *= Pp; }
    }
    if (lane == 63) { sP[w] = Pi; sH[w] = hi; }
    __syncthreads();
    float Hw = 0.f, Pw = 1.f;
    for (int qq = 0; qq < w; qq++) { Hw = fmaf(Hw, sP[qq], sH[qq]); Pw *= sP[qq]; }

    const float hloc = fmaf(Hw, Pi, hi);
    const float pinc = Pw * Pi;
    g_hp[(size_t)chain * NSEQ + t] = make_float2(hloc, pinc);
    if (tid == 255)
        g_sum[chain * 16 + chunk] = make_float2(hloc, pinc);
}

// ---------------------------------------------------------------------------
// k3: carry-in H from <=15 chunk summaries, h = fma(P_inc, H, h_loc) into a
// 16x20 LDS tile (b128 broadcast reads), then y = h@C (+ x*D slow path).
// (unchanged from round 10)
// ---------------------------------------------------------------------------
__global__ __launch_bounds__(256) void k3_out(const float* __restrict__ x,
                                              const float* __restrict__ C,
                                              const float* __restrict__ D,
                                              float* __restrict__ out) {
    __shared__ __align__(16) float sh[16 * 20];
    const int tid = threadIdx.x;
    const int blk = blockIdx.x;
    const int tc  = blk & 255;
    const int b   = blk >> 8;
    const int t0  = tc * 16;

    {
        const int s  = tid >> 4;
        const int tt = tid & 15;
        const int chain = b * 16 + s;
        const int t = t0 + tt;
        const int chunk = t >> 8;
        float H = 0.f;
        for (int c = 0; c < chunk; ++c) {
            const float2 su = g_sum[chain * 16 + c];
            H = fmaf(H, su.y, su.x);
        }
        const float2 hp = g_hp[(size_t)chain * NSEQ + t];
        sh[tt * 20 + s] = fmaf(hp.y, H, hp.x);
    }

    const float4* C4 = (const float4*)C;
    float4 creg[16];
#pragma unroll
    for (int s = 0; s < 16; s++) creg[s] = C4[s * 256 + tid];
    const float4 dreg = ((const float4*)D)[tid];
    const bool needX = __any((dreg.x != 0.f) | (dreg.y != 0.f) |
                             (dreg.z != 0.f) | (dreg.w != 0.f));
    __syncthreads();

    const float4* x4 = (const float4*)x;
    float4* o4 = (float4*)out;
    const size_t rowbase = ((size_t)b * NSEQ + t0) * 256;

    if (needX) {
#pragma unroll 4
        for (int tt = 0; tt < 16; tt++) {
            float4 xv = x4[rowbase + tt * 256 + tid];
            float4 y;
            y.x = xv.x * dreg.x; y.y = xv.y * dreg.y;
            y.z = xv.z * dreg.z; y.w = xv.w * dreg.w;
#pragma unroll
            for (int g = 0; g < 4; g++) {
                const float4 h4 = *(const float4*)&sh[tt * 20 + g * 4];
                fma4(y, h4.x, creg[g * 4 + 0]);
                fma4(y, h4.y, creg[g * 4 + 1]);
                fma4(y, h4.z, creg[g * 4 + 2]);
                fma4(y, h4.w, creg[g * 4 + 3]);
            }
            o4[rowbase + tt * 256 + tid] = y;
        }
    } else {
#pragma unroll 4
        for (int tt = 0; tt < 16; tt++) {
            float4 y = make_float4(0.f, 0.f, 0.f, 0.f);
#pragma unroll
            for (int g = 0; g < 4; g++) {
                const float4 h4 = *(const float4*)&sh[tt * 20 + g * 4];
                fma4(y, h4.x, creg[g * 4 + 0]);
                fma4(y, h4.y, creg[g * 4 + 1]);
                fma4(y, h4.z, creg[g * 4 + 2]);
                fma4(y, h4.w, creg[g * 4 + 3]);
            }
            o4[rowbase + tt * 256 + tid] = y;
        }
    }
}

extern "C" void kernel_launch(void* const* d_in, const int* in_sizes, int n_in,
                              void* d_out, int out_size, void* d_ws, size_t ws_size,
                              hipStream_t stream) {
    const float* x   = (const float*)d_in[0];
    const float* A   = (const float*)d_in[1];
    const float* Bin = (const float*)d_in[2];
    const float* C   = (const float*)d_in[3];
    const float* D   = (const float*)d_in[4];
    float* out = (float*)d_out;
    (void)d_ws; (void)ws_size;

    hipLaunchKernelGGL(k1_bx,   dim3(1024), dim3(256), 0, stream, x, Bin);
    hipLaunchKernelGGL(k2_scan, dim3(1024), dim3(256), 0, stream, A);
    hipLaunchKernelGGL(k3_out,  dim3(1024), dim3(256), 0, stream, x, C, D, out);
}

// Round 13
// 140.504 us; speedup vs baseline: 1.0782x; 1.0782x over previous
//
#include <hip/hip_runtime.h>

#define NSEQ 4096
#define EDIM 1024

// Cross-dispatch intermediates in __device__ globals (round 10: harness
// re-poisons d_ws unconditionally; globals are clean).
// Every element is fully rewritten each iteration before any read.
__device__ float  g_pbx[8 * 64 * NSEQ];   // partial Bx [8 e-8ths][64 chain][4096 t]
__device__ float2 g_hp [64 * NSEQ];       // {h_loc, P_inc} [64 chain][4096 t]
__device__ float2 g_sum[64 * 16];         // {h_last, P_prod} [64 chain][16 chunk]

__device__ __forceinline__ void fma4(float4& a, float xv, const float4& b) {
    a.x = fmaf(xv, b.x, a.x);
    a.y = fmaf(xv, b.y, a.y);
    a.z = fmaf(xv, b.z, a.z);
    a.w = fmaf(xv, b.w, a.w);
}

// ---------------------------------------------------------------------------
// k1: partial Bx = x @ B_in over one e-EIGHTH (128 e). Single-variable change
// vs round-10 (best k1, ~30us): block geometry only — 2048 blocks x 256 thr
// = 8 blocks/CU, 32 waves/CU (100% occupancy; all prior k1 variants ran at
// <=50%). Evidence: k1 duration tracks per-thread loads-in-flight (2-deep=44,
// 4-deep=46, 16-deep=30us) -> latency x bytes-in-flight bound; doubling
// resident waves doubles aggregate MLP. Per-thread structure is a halved
// clone of round-10: 8 contiguous float4 of x loaded up front (128B/thread),
// wave-uniform e -> B via s_loads (B-path proven perf-neutral R9/R11), same
// [4][64][17] LDS reduction. launch_bounds(256,8): VGPR cap 64, demand ~60.
// LDS 17.4 KB x 8 blocks = 139 KB <= 160.
// ---------------------------------------------------------------------------
__global__ __launch_bounds__(256, 8) void k1_bx(const float* __restrict__ x,
                                                const float* __restrict__ Bin) {
    __shared__ float red[4 * 64 * 17];   // 17.4 KB (reduction only)
    const int tid  = threadIdx.x;
    const int lane = tid & 63;                                  // row
    const int wu   = __builtin_amdgcn_readfirstlane(tid) >> 6;  // wave id
    const int q8   = blockIdx.x & 7;                            // e-eighth
    const int r0   = (blockIdx.x >> 3) * 64;                    // row base
    const int b    = r0 >> 12;
    const int n0   = r0 & 4095;
    const int eb   = q8 * 128;                                  // e base

    const float4* xf4 = (const float4*)x;
    const float4* Bf4 = (const float4*)Bin;

    // this thread's x: row r0+lane, e in [eb + wu*32, +32) = 8 float4,
    // contiguous 128B — all 8 loads issued up front (8-deep per-thread MLP,
    // x 32 waves/CU resident).
    float4 xr[8];
    const size_t rowb = (size_t)(r0 + lane) * 256 + q8 * 32 + wu * 8;
#pragma unroll
    for (int j = 0; j < 8; j++) xr[j] = xf4[rowb + j];

    float acc[16];
#pragma unroll
    for (int s = 0; s < 16; s++) acc[s] = 0.f;

#pragma unroll
    for (int j = 0; j < 8; ++j) {
        const float4 xq = xr[j];
        const float xs[4] = {xq.x, xq.y, xq.z, xq.w};
#pragma unroll
        for (int m = 0; m < 4; ++m) {
            const int e = eb + wu * 32 + j * 4 + m;   // wave-uniform -> s_load
            const float4 b0 = Bf4[e * 4 + 0];
            const float4 b1 = Bf4[e * 4 + 1];
            const float4 b2 = Bf4[e * 4 + 2];
            const float4 b3 = Bf4[e * 4 + 3];
            const float xv = xs[m];
            acc[0]  = fmaf(xv, b0.x, acc[0]);  acc[1]  = fmaf(xv, b0.y, acc[1]);
            acc[2]  = fmaf(xv, b0.z, acc[2]);  acc[3]  = fmaf(xv, b0.w, acc[3]);
            acc[4]  = fmaf(xv, b1.x, acc[4]);  acc[5]  = fmaf(xv, b1.y, acc[5]);
            acc[6]  = fmaf(xv, b1.z, acc[6]);  acc[7]  = fmaf(xv, b1.w, acc[7]);
            acc[8]  = fmaf(xv, b2.x, acc[8]);  acc[9]  = fmaf(xv, b2.y, acc[9]);
            acc[10] = fmaf(xv, b2.z, acc[10]); acc[11] = fmaf(xv, b2.w, acc[11]);
            acc[12] = fmaf(xv, b3.x, acc[12]); acc[13] = fmaf(xv, b3.y, acc[13]);
            acc[14] = fmaf(xv, b3.z, acc[14]); acc[15] = fmaf(xv, b3.w, acc[15]);
        }
    }

    // cross-wave reduction: red[4 waves][64 rows][17]
    {
        const int rb = (wu * 64 + lane) * 17;
#pragma unroll
        for (int s = 0; s < 16; s++) red[rb + s] = acc[s];
    }
    __syncthreads();

#pragma unroll
    for (int p = 0; p < 4; p++) {
        const int o   = tid + 256 * p;
        const int s   = o >> 6;      // wave-uniform
        const int row = o & 63;
        const float v = red[(0 * 64 + row) * 17 + s] + red[(1 * 64 + row) * 17 + s] +
                        red[(2 * 64 + row) * 17 + s] + red[(3 * 64 + row) * 17 + s];
        g_pbx[(size_t)q8 * 262144u + (size_t)(b * 16 + s) * NSEQ + n0 + row] = v;
    }
}

// ---------------------------------------------------------------------------
// k2: sum 8 partial-Bx eighths, softplus -> decay, 256-wide chunk-local
// scan. 1024 blocks x 256 threads. (only change vs round 10: 8-way sum)
// ---------------------------------------------------------------------------
__global__ __launch_bounds__(256) void k2_scan(const float* __restrict__ A) {
    __shared__ float sP[4], sH[4];
    const int tid   = threadIdx.x;
    const int lane  = tid & 63;
    const int w     = tid >> 6;
    const int chain = blockIdx.x >> 4;
    const int chunk = blockIdx.x & 15;
    const int ss    = chain & 15;
    const int t     = chunk * 256 + tid;

    float bxv = 0.f;
#pragma unroll
    for (int q = 0; q < 8; q++)
        bxv += g_pbx[(size_t)q * 262144u + (size_t)chain * NSEQ + t];

    const float Ae = expf(A[ss]);
    const float sp = fmaxf(bxv, 0.f) + log1pf(expf(-fabsf(bxv)));
    const float de = expf(-Ae * sp);

    float Pi = de, hi = bxv;
#pragma unroll
    for (int off = 1; off < 64; off <<= 1) {
        float Pp = __shfl_up(Pi, off, 64);
        float hp = __shfl_up(hi, off, 64);
        if (lane >= off) { hi = fmaf(hp, Pi, hi); Pi *= Pp; }
    }
    if (lane == 63) { sP[w] = Pi; sH[w] = hi; }
    __syncthreads();
    float Hw = 0.f, Pw = 1.f;
    for (int qq = 0; qq < w; qq++) { Hw = fmaf(Hw, sP[qq], sH[qq]); Pw *= sP[qq]; }

    const float hloc = fmaf(Hw, Pi, hi);
    const float pinc = Pw * Pi;
    g_hp[(size_t)chain * NSEQ + t] = make_float2(hloc, pinc);
    if (tid == 255)
        g_sum[chain * 16 + chunk] = make_float2(hloc, pinc);
}

// ---------------------------------------------------------------------------
// k3: carry-in H from <=15 chunk summaries, h = fma(P_inc, H, h_loc) into a
// 16x20 LDS tile (b128 broadcast reads), then y = h@C (+ x*D slow path).
// (unchanged from round 10)
// ---------------------------------------------------------------------------
__global__ __launch_bounds__(256) void k3_out(const float* __restrict__ x,
                                              const float* __restrict__ C,
                                              const float* __restrict__ D,
                                              float* __restrict__ out) {
    __shared__ __align__(16) float sh[16 * 20];
    const int tid = threadIdx.x;
    const int blk = blockIdx.x;
    const int tc  = blk & 255;
    const int b   = blk >> 8;
    const int t0  = tc * 16;

    {
        const int s  = tid >> 4;
        const int tt = tid & 15;
        const int chain = b * 16 + s;
        const int t = t0 + tt;
        const int chunk = t >> 8;
        float H = 0.f;
        for (int c = 0; c < chunk; ++c) {
            const float2 su = g_sum[chain * 16 + c];
            H = fmaf(H, su.y, su.x);
        }
        const float2 hp = g_hp[(size_t)chain * NSEQ + t];
        sh[tt * 20 + s] = fmaf(hp.y, H, hp.x);
    }

    const float4* C4 = (const float4*)C;
    float4 creg[16];
#pragma unroll
    for (int s = 0; s < 16; s++) creg[s] = C4[s * 256 + tid];
    const float4 dreg = ((const float4*)D)[tid];
    const bool needX = __any((dreg.x != 0.f) | (dreg.y != 0.f) |
                             (dreg.z != 0.f) | (dreg.w != 0.f));
    __syncthreads();

    const float4* x4 = (const float4*)x;
    float4* o4 = (float4*)out;
    const size_t rowbase = ((size_t)b * NSEQ + t0) * 256;

    if (needX) {
#pragma unroll 4
        for (int tt = 0; tt < 16; tt++) {
            float4 xv = x4[rowbase + tt * 256 + tid];
            float4 y;
            y.x = xv.x * dreg.x; y.y = xv.y * dreg.y;
            y.z = xv.z * dreg.z; y.w = xv.w * dreg.w;
#pragma unroll
            for (int g = 0; g < 4; g++) {
                const float4 h4 = *(const float4*)&sh[tt * 20 + g * 4];
                fma4(y, h4.x, creg[g * 4 + 0]);
                fma4(y, h4.y, creg[g * 4 + 1]);
                fma4(y, h4.z, creg[g * 4 + 2]);
                fma4(y, h4.w, creg[g * 4 + 3]);
            }
            o4[rowbase + tt * 256 + tid] = y;
        }
    } else {
#pragma unroll 4
        for (int tt = 0; tt < 16; tt++) {
            float4 y = make_float4(0.f, 0.f, 0.f, 0.f);
#pragma unroll
            for (int g = 0; g < 4; g++) {
                const float4 h4 = *(const float4*)&sh[tt * 20 + g * 4];
                fma4(y, h4.x, creg[g * 4 + 0]);
                fma4(y, h4.y, creg[g * 4 + 1]);
                fma4(y, h4.z, creg[g * 4 + 2]);
                fma4(y, h4.w, creg[g * 4 + 3]);
            }
            o4[rowbase + tt * 256 + tid] = y;
        }
    }
}

extern "C" void kernel_launch(void* const* d_in, const int* in_sizes, int n_in,
                              void* d_out, int out_size, void* d_ws, size_t ws_size,
                              hipStream_t stream) {
    const float* x   = (const float*)d_in[0];
    const float* A   = (const float*)d_in[1];
    const float* Bin = (const float*)d_in[2];
    const float* C   = (const float*)d_in[3];
    const float* D   = (const float*)d_in[4];
    float* out = (float*)d_out;
    (void)d_ws; (void)ws_size;

    hipLaunchKernelGGL(k1_bx,   dim3(2048), dim3(256), 0, stream, x, Bin);
    hipLaunchKernelGGL(k2_scan, dim3(1024), dim3(256), 0, stream, A);
    hipLaunchKernelGGL(k3_out,  dim3(1024), dim3(256), 0, stream, x, C, D, out);
}

// Round 14
// 135.604 us; speedup vs baseline: 1.1172x; 1.0361x over previous
//
#include <hip/hip_runtime.h>

#define NSEQ 4096
#define EDIM 1024

// ws layout (float offsets)
#define OFF_PBX 0u         // partial Bx [4 q][64 chain][4096 t]      = 4 MB
#define OFF_HP  1048576u   // {h_loc, P_inc} [64 chain][4096] float2  = 2 MB
#define OFF_SUM 2097152u   // {h_last, P_prod} [64 chain][16] float2  = 8 KB

__device__ __forceinline__ void fma4(float4& a, float xv, const float4& b) {
    a.x = fmaf(xv, b.x, a.x);
    a.y = fmaf(xv, b.y, a.y);
    a.z = fmaf(xv, b.z, a.z);
    a.w = fmaf(xv, b.w, a.w);
}

// ---------------------------------------------------------------------------
// k1: partial Bx = x @ B_in over one e-quarter (256 e), NO LDS staging
// (waves partition e -> zero cross-wave x reuse). 1024 blocks x 256 threads
// = 4 blocks/CU, 16 waves/CU. Each thread (row = lane) loads its 16 float4
// of x directly into registers (16-deep MLP — measured best across 2/4/8/16);
// B wave-uniform -> s_loads (operand path proven perf-neutral vs LDS, R9/R11).
// One barrier total. Best-measured k1 config (R6: total 134.0 us).
// ---------------------------------------------------------------------------
__global__ __launch_bounds__(256, 4) void k1_bx(const float* __restrict__ x,
                                                const float* __restrict__ Bin,
                                                float* __restrict__ ws) {
    __shared__ float red[4 * 64 * 17];   // 17.4 KB (reduction only)
    const int tid  = threadIdx.x;
    const int lane = tid & 63;                                  // row
    const int wu   = __builtin_amdgcn_readfirstlane(tid) >> 6;  // wave id
    const int q    = blockIdx.x & 3;                            // e-quarter
    const int r0   = (blockIdx.x >> 2) * 64;                    // row base
    const int b    = r0 >> 12;
    const int n0   = r0 & 4095;
    const int eq   = q * 256;

    const float4* xf4 = (const float4*)x;
    const float4* Bf4 = (const float4*)Bin;

    // this thread's x: row r0+lane, e-locals {c*64 + wu*16 + 0..15}, c=0..3
    float4 xr[16];
    const size_t rowb = (size_t)(r0 + lane) * 256 + q * 64 + wu * 4;
#pragma unroll
    for (int c = 0; c < 4; c++)
#pragma unroll
        for (int jj = 0; jj < 4; jj++)
            xr[c * 4 + jj] = xf4[rowb + c * 16 + jj];

    float acc[16];
#pragma unroll
    for (int s = 0; s < 16; s++) acc[s] = 0.f;

#pragma unroll
    for (int c = 0; c < 4; ++c) {
#pragma unroll
        for (int jj = 0; jj < 4; ++jj) {
            const float4 xq = xr[c * 4 + jj];
            const float xs[4] = {xq.x, xq.y, xq.z, xq.w};
#pragma unroll
            for (int m = 0; m < 4; ++m) {
                const int e = eq + c * 64 + wu * 16 + jj * 4 + m;  // wave-uniform
                const float4 b0 = Bf4[e * 4 + 0];
                const float4 b1 = Bf4[e * 4 + 1];
                const float4 b2 = Bf4[e * 4 + 2];
                const float4 b3 = Bf4[e * 4 + 3];
                const float xv = xs[m];
                acc[0]  = fmaf(xv, b0.x, acc[0]);  acc[1]  = fmaf(xv, b0.y, acc[1]);
                acc[2]  = fmaf(xv, b0.z, acc[2]);  acc[3]  = fmaf(xv, b0.w, acc[3]);
                acc[4]  = fmaf(xv, b1.x, acc[4]);  acc[5]  = fmaf(xv, b1.y, acc[5]);
                acc[6]  = fmaf(xv, b1.z, acc[6]);  acc[7]  = fmaf(xv, b1.w, acc[7]);
                acc[8]  = fmaf(xv, b2.x, acc[8]);  acc[9]  = fmaf(xv, b2.y, acc[9]);
                acc[10] = fmaf(xv, b2.z, acc[10]); acc[11] = fmaf(xv, b2.w, acc[11]);
                acc[12] = fmaf(xv, b3.x, acc[12]); acc[13] = fmaf(xv, b3.y, acc[13]);
                acc[14] = fmaf(xv, b3.z, acc[14]); acc[15] = fmaf(xv, b3.w, acc[15]);
            }
        }
    }

    // cross-wave reduction: red[4 waves][64 rows][17]
    {
        const int rb = (wu * 64 + lane) * 17;
#pragma unroll
        for (int s = 0; s < 16; s++) red[rb + s] = acc[s];
    }
    __syncthreads();

#pragma unroll
    for (int p = 0; p < 4; p++) {
        const int o   = tid + 256 * p;
        const int s   = o >> 6;      // wave-uniform
        const int row = o & 63;
        const float v = red[(0 * 64 + row) * 17 + s] + red[(1 * 64 + row) * 17 + s] +
                        red[(2 * 64 + row) * 17 + s] + red[(3 * 64 + row) * 17 + s];
        ws[OFF_PBX + (size_t)q * 262144u + (size_t)(b * 16 + s) * NSEQ + n0 + row] = v;
    }
}

// ---------------------------------------------------------------------------
// k2: sum 4 partial-Bx quarters, softplus -> decay, 256-wide chunk-local
// scan. 1024 blocks x 256 threads; block = (chain, 256-step chunk). Wave
// scan + 4-wave LDS combine. Writes {h_loc,P_inc} + chunk summary;
// cross-chunk prefix folded into k3 (dispatch boundary = free barrier).
// ---------------------------------------------------------------------------
__global__ __launch_bounds__(256) void k2_scan(const float* __restrict__ A,
                                               float* __restrict__ ws) {
    __shared__ float sP[4], sH[4];
    const int tid   = threadIdx.x;
    const int lane  = tid & 63;
    const int w     = tid >> 6;
    const int chain = blockIdx.x >> 4;
    const int chunk = blockIdx.x & 15;
    const int ss    = chain & 15;
    const int t     = chunk * 256 + tid;

    float bxv = 0.f;
#pragma unroll
    for (int q = 0; q < 4; q++)
        bxv += ws[OFF_PBX + (size_t)q * 262144u + (size_t)chain * NSEQ + t];

    const float Ae = expf(A[ss]);
    const float sp = fmaxf(bxv, 0.f) + log1pf(expf(-fabsf(bxv)));
    const float de = expf(-Ae * sp);

    // wave-inclusive scan of (P,h): h' = h_left*P_right + h_right
    float Pi = de, hi = bxv;
#pragma unroll
    for (int off = 1; off < 64; off <<= 1) {
        float Pp = __shfl_up(Pi, off, 64);
        float hp = __shfl_up(hi, off, 64);
        if (lane >= off) { hi = fmaf(hp, Pi, hi); Pi *= Pp; }
    }
    if (lane == 63) { sP[w] = Pi; sH[w] = hi; }
    __syncthreads();
    float Hw = 0.f, Pw = 1.f;
    for (int qq = 0; qq < w; qq++) { Hw = fmaf(Hw, sP[qq], sH[qq]); Pw *= sP[qq]; }

    const float hloc = fmaf(Hw, Pi, hi);   // inclusive within chunk
    const float pinc = Pw * Pi;            // product of de over [chunk start, t]
    ((float2*)(ws + OFF_HP))[(size_t)chain * NSEQ + t] = make_float2(hloc, pinc);
    if (tid == 255)   // whole-chunk summary (h_last, P_prod)
        ((float2*)(ws + OFF_SUM))[chain * 16 + chunk] = make_float2(hloc, pinc);
}

// ---------------------------------------------------------------------------
// k3: carry-in H = fma-scan of <=15 chunk summaries (8 KB, L2-hot), then
// h = fma(P_inc, H, h_loc) into a 16x20 LDS tile (pitch 20: 16B-aligned per
// row -> broadcast ds_read_b128), then y[b,t,e] = sum_s h[t,s]*C[s,e]
// (+ x*D slow path; D == 0 here so the x read is skipped). 1024 x 256.
// ---------------------------------------------------------------------------
__global__ __launch_bounds__(256) void k3_out(const float* __restrict__ x,
                                              const float* __restrict__ C,
                                              const float* __restrict__ D,
                                              const float* __restrict__ ws,
                                              float* __restrict__ out) {
    __shared__ __align__(16) float sh[16 * 20];
    const int tid = threadIdx.x;
    const int blk = blockIdx.x;
    const int tc  = blk & 255;
    const int b   = blk >> 8;
    const int t0  = tc * 16;

    {   // reconstruct h[tt][s]: thread (s = tid>>4, tt = tid&15)
        const int s  = tid >> 4;
        const int tt = tid & 15;
        const int chain = b * 16 + s;
        const int t = t0 + tt;
        const int chunk = t >> 8;          // uniform per block
        const float2* SU = (const float2*)(ws + OFF_SUM);
        float H = 0.f;                     // scan state entering this chunk
        for (int c = 0; c < chunk; ++c) {
            const float2 su = SU[chain * 16 + c];
            H = fmaf(H, su.y, su.x);
        }
        const float2 hp = ((const float2*)(ws + OFF_HP))[(size_t)chain * NSEQ + t];
        sh[tt * 20 + s] = fmaf(hp.y, H, hp.x);
    }

    const float4* C4 = (const float4*)C;  // [16][256] float4
    float4 creg[16];
#pragma unroll
    for (int s = 0; s < 16; s++) creg[s] = C4[s * 256 + tid];
    const float4 dreg = ((const float4*)D)[tid];
    const bool needX = __any((dreg.x != 0.f) | (dreg.y != 0.f) |
                             (dreg.z != 0.f) | (dreg.w != 0.f));
    __syncthreads();

    const float4* x4 = (const float4*)x;
    float4* o4 = (float4*)out;
    const size_t rowbase = ((size_t)b * NSEQ + t0) * 256;

    if (needX) {
#pragma unroll 4
        for (int tt = 0; tt < 16; tt++) {
            float4 xv = x4[rowbase + tt * 256 + tid];
            float4 y;
            y.x = xv.x * dreg.x; y.y = xv.y * dreg.y;
            y.z = xv.z * dreg.z; y.w = xv.w * dreg.w;
#pragma unroll
            for (int g = 0; g < 4; g++) {
                const float4 h4 = *(const float4*)&sh[tt * 20 + g * 4];
                fma4(y, h4.x, creg[g * 4 + 0]);
                fma4(y, h4.y, creg[g * 4 + 1]);
                fma4(y, h4.z, creg[g * 4 + 2]);
                fma4(y, h4.w, creg[g * 4 + 3]);
            }
            o4[rowbase + tt * 256 + tid] = y;
        }
    } else {
#pragma unroll 4
        for (int tt = 0; tt < 16; tt++) {
            float4 y = make_float4(0.f, 0.f, 0.f, 0.f);
#pragma unroll
            for (int g = 0; g < 4; g++) {
                const float4 h4 = *(const float4*)&sh[tt * 20 + g * 4];
                fma4(y, h4.x, creg[g * 4 + 0]);
                fma4(y, h4.y, creg[g * 4 + 1]);
                fma4(y, h4.z, creg[g * 4 + 2]);
                fma4(y, h4.w, creg[g * 4 + 3]);
            }
            o4[rowbase + tt * 256 + tid] = y;
        }
    }
}

extern "C" void kernel_launch(void* const* d_in, const int* in_sizes, int n_in,
                              void* d_out, int out_size, void* d_ws, size_t ws_size,
                              hipStream_t stream) {
    const float* x   = (const float*)d_in[0];
    const float* A   = (const float*)d_in[1];
    const float* Bin = (const float*)d_in[2];
    const float* C   = (const float*)d_in[3];
    const float* D   = (const float*)d_in[4];
    float* out = (float*)d_out;
    float* ws  = (float*)d_ws;

    hipLaunchKernelGGL(k1_bx,   dim3(1024), dim3(256), 0, stream, x, Bin, ws);
    hipLaunchKernelGGL(k2_scan, dim3(1024), dim3(256), 0, stream, A, ws);
    hipLaunchKernelGGL(k3_out,  dim3(1024), dim3(256), 0, stream, x, C, D, ws, out);
}